// Round 5
// baseline (22.464 us; speedup 1.0000x reference)
//
#include <hip/hip_runtime.h>

#define N_SAMPLES 128
#define NUM_OBJECTS 8
#define NUM_POINTS 100000
#define GROUPS 25000           // groups of 4 points (48 B / 12 floats each)
#define TPB 256
#define CHUNKS 64              // 64 blocks/object * 256 thr * 2 groups = 32768 >= 25000
#define MAXS 128

// ---- ws layout (floats) ----
// [0 .. 8192)                partials [128][CHUNKS]
// [8192 .. 8200)             per-object counts (as int)
// [8200 .. 9224)             per-object sample lists int[8][128]
// [9224 .. 21512)            dR tables float[8][128][12]  (16B aligned: 9224%4==0)
#define WS_PART 0
#define WS_CNT  8192
#define WS_SIDX 8200
#define WS_DR   9224

// 4 packed points from 12 floats f[0..11]:
// p0=(f0,f1,f2) p1=(f3,f4,f5) p2=(f6,f7,f8) p3=(f9,f10,f11)
__device__ __forceinline__ float pts4_l1(
    const float* __restrict__ f,
    float d0, float d1, float d2, float d3, float d4,
    float d5, float d6, float d7, float d8)
{
    float s;
    s  = fabsf(d0 * f[0] + d1 * f[1]  + d2 * f[2])
       + fabsf(d3 * f[0] + d4 * f[1]  + d5 * f[2])
       + fabsf(d6 * f[0] + d7 * f[1]  + d8 * f[2]);
    s += fabsf(d0 * f[3] + d1 * f[4]  + d2 * f[5])
       + fabsf(d3 * f[3] + d4 * f[4]  + d5 * f[5])
       + fabsf(d6 * f[3] + d7 * f[4]  + d8 * f[5]);
    s += fabsf(d0 * f[6] + d1 * f[7]  + d2 * f[8])
       + fabsf(d3 * f[6] + d4 * f[7]  + d5 * f[8])
       + fabsf(d6 * f[6] + d7 * f[7]  + d8 * f[8]);
    s += fabsf(d0 * f[9] + d1 * f[10] + d2 * f[11])
       + fabsf(d3 * f[9] + d4 * f[10] + d5 * f[11])
       + fabsf(d6 * f[9] + d7 * f[10] + d8 * f[11]);
    return s;
}

// Kernel 0: one block. Build compact per-object tables in ws and emit the
// two translation losses. Main-kernel prologue becomes a straight copy.
__global__ __launch_bounds__(256) void prep_kernel(
    const int* __restrict__ obj_id,
    const float* __restrict__ gtR, const float* __restrict__ prR,
    const float* __restrict__ gt_t, const float* __restrict__ pred_t,
    float* __restrict__ ws, float* __restrict__ out)
{
    __shared__ int s_cnt[NUM_OBJECTS];
    const int t = threadIdx.x;
    if (t < NUM_OBJECTS) s_cnt[t] = 0;
    __syncthreads();
    if (t < N_SAMPLES) {
        const int n = t;
        const int o = obj_id[n];
        const int slot = atomicAdd(&s_cnt[o], 1);
        ((int*)(ws + WS_SIDX))[o * MAXS + slot] = n;
        float* dr = ws + WS_DR + ((size_t)o * MAXS + slot) * 12;
        #pragma unroll
        for (int j = 0; j < 9; ++j)
            dr[j] = prR[n * 9 + j] - gtR[n * 9 + j];
        dr[9] = 0.0f; dr[10] = 0.0f; dr[11] = 0.0f;
        // translation losses
        out[N_SAMPLES + n] = fabsf(gt_t[n * 3 + 0] - pred_t[n * 3 + 0])
                           + fabsf(gt_t[n * 3 + 1] - pred_t[n * 3 + 1]);
        out[2 * N_SAMPLES + n] = fabsf(gt_t[n * 3 + 2] - pred_t[n * 3 + 2]);
    }
    __syncthreads();
    if (t < NUM_OBJECTS) ((int*)(ws + WS_CNT))[t] = s_cnt[t];
}

// Kernel 1: grid = (CHUNKS, NUM_OBJECTS). Each thread holds 8 points (two
// groups of 4) in registers; samples processed 4 at a time; 5-level
// within-32 __shfl_xor reduce; one plain ws store per (sample, chunk).
__global__ __launch_bounds__(TPB) void pm_partial_kernel(
    const float* __restrict__ pts, float* __restrict__ ws)
{
    const int o     = blockIdx.y;
    const int chunk = blockIdx.x;
    const int tid   = threadIdx.x;

    const int nsamp = ((const int*)(ws + WS_CNT))[o];
    if (nsamp == 0) return;
    const int nsamp_pad = (nsamp + 3) & ~3;

    __shared__ float s_dR[MAXS][12];
    __shared__ int   s_sidx[MAXS];
    __shared__ float s_part[8][MAXS];

    // straight cooperative copy of the precomputed tables (zero the pad rows)
    const float4* __restrict__ dR4 =
        (const float4*)(ws + WS_DR + (size_t)o * MAXS * 12);
    float4* s_dR4 = (float4*)&s_dR[0][0];
    for (int i = tid; i < nsamp_pad * 3; i += TPB)
        s_dR4[i] = (i < nsamp * 3) ? dR4[i] : make_float4(0.f, 0.f, 0.f, 0.f);
    const int* __restrict__ sidx = (const int*)(ws + WS_SIDX) + o * MAXS;
    if (tid < nsamp) s_sidx[tid] = sidx[tid];
    __syncthreads();

    // Load this thread's 8 points (two groups) once.
    const float4* __restrict__ p4 =
        (const float4*)(pts + (size_t)o * (size_t)NUM_POINTS * 3);
    const int g0 = chunk * TPB + tid;            // < 16384 < GROUPS: always valid
    const int g1 = g0 + CHUNKS * TPB;            // may exceed GROUPS
    float4 a0 = p4[g0 * 3 + 0], b0 = p4[g0 * 3 + 1], c0 = p4[g0 * 3 + 2];
    const float valid = (g1 < GROUPS) ? 1.0f : 0.0f;
    const int g1c = min(g1, GROUPS - 1);
    float4 a1 = p4[g1c * 3 + 0], b1 = p4[g1c * 3 + 1], c1 = p4[g1c * 3 + 2];
    float f0[12] = { a0.x, a0.y, a0.z, a0.w, b0.x, b0.y,
                     b0.z, b0.w, c0.x, c0.y, c0.z, c0.w };
    float f1[12] = { a1.x * valid, a1.y * valid, a1.z * valid, a1.w * valid,
                     b1.x * valid, b1.y * valid, b1.z * valid, b1.w * valid,
                     c1.x * valid, c1.y * valid, c1.z * valid, c1.w * valid };

    const int lane = tid & 63;
    const int half = (tid >> 6) * 2 + ((lane >> 5) & 1);

    for (int s0 = 0; s0 < nsamp_pad; s0 += 4) {
        float acc[4];
        #pragma unroll
        for (int k = 0; k < 4; ++k) {
            float4 q0 = *(const float4*)&s_dR[s0 + k][0];
            float4 q1 = *(const float4*)&s_dR[s0 + k][4];
            float4 q2 = *(const float4*)&s_dR[s0 + k][8];
            acc[k] = pts4_l1(f0, q0.x, q0.y, q0.z, q0.w,
                                 q1.x, q1.y, q1.z, q1.w, q2.x)
                   + pts4_l1(f1, q0.x, q0.y, q0.z, q0.w,
                                 q1.x, q1.y, q1.z, q1.w, q2.x);
        }
        #pragma unroll
        for (int off = 1; off <= 16; off <<= 1) {
            #pragma unroll
            for (int k = 0; k < 4; ++k)
                acc[k] += __shfl_xor(acc[k], off, 64);
        }
        if ((lane & 31) == 0) {
            #pragma unroll
            for (int k = 0; k < 4; ++k)
                s_part[half][s0 + k] = acc[k];
        }
    }
    __syncthreads();

    if (tid < nsamp) {
        float v = 0.0f;
        #pragma unroll
        for (int w = 0; w < 8; ++w) v += s_part[w][tid];
        ws[WS_PART + (size_t)s_sidx[tid] * CHUNKS + chunk] = v;
    }
}

// Kernel 2: one wave per sample reduces the CHUNKS partials and scales.
__global__ __launch_bounds__(64) void finish_kernel(
    const int* __restrict__ obj_id, const float* __restrict__ diam,
    const float* __restrict__ ws, float* __restrict__ out)
{
    const int n = blockIdx.x;
    const int t = threadIdx.x;
    float v = ws[WS_PART + (size_t)n * CHUNKS + t];   // CHUNKS == 64 == blockDim
    #pragma unroll
    for (int off = 1; off <= 32; off <<= 1)
        v += __shfl_xor(v, off, 64);
    if (t == 0)
        out[n] = v / ((float)NUM_POINTS * diam[obj_id[n]]);
}

extern "C" void kernel_launch(void* const* d_in, const int* in_sizes, int n_in,
                              void* d_out, int out_size, void* d_ws, size_t ws_size,
                              hipStream_t stream) {
    const int*   obj_id = (const int*)d_in[0];
    const float* gtR    = (const float*)d_in[1];
    const float* prR    = (const float*)d_in[2];
    const float* gt_t   = (const float*)d_in[3];
    const float* pred_t = (const float*)d_in[4];
    const float* pts    = (const float*)d_in[5];
    const float* diam   = (const float*)d_in[6];
    float* out = (float*)d_out;
    float* ws  = (float*)d_ws;   // ~86 KB used

    prep_kernel<<<1, 256, 0, stream>>>(obj_id, gtR, prR, gt_t, pred_t, ws, out);
    pm_partial_kernel<<<dim3(CHUNKS, NUM_OBJECTS), TPB, 0, stream>>>(pts, ws);
    finish_kernel<<<N_SAMPLES, 64, 0, stream>>>(obj_id, diam, ws, out);
}